// Round 2
// baseline (310.607 us; speedup 1.0000x reference)
//
#include <hip/hip_runtime.h>

#define H_DIM 768
#define C_DIM 512
#define L_DIM 256
#define S_DIM 2048
#define B_DIM 16

#define IA_STRIDE 520   // 512 + 8: lane stride 1040B = 260 dw = 4 mod 32 banks
#define ATTN_STRIDE 264 // 256 + 8: lane stride 528B = 132 dw = 4 mod 32 banks
#define XP_STRIDE 776   // 768 + 8 (f16): row stride 1552B, 16B-aligned, 2-way conflict (free)

typedef __attribute__((ext_vector_type(8))) short short8;
typedef __attribute__((ext_vector_type(4))) float f32x4;
typedef __attribute__((ext_vector_type(2))) __fp16 half2v;   // cvt_pkrtz return type

#define MFMA_F16(a, b, c) __builtin_amdgcn_mfma_f32_16x16x32_f16((a), (b), (c), 0, 0, 0)

__device__ __forceinline__ unsigned short f2h(float f) {
    _Float16 h = (_Float16)f;
    return __builtin_bit_cast(unsigned short, h);
}
__device__ __forceinline__ float h2f(unsigned short u) {
    _Float16 h = __builtin_bit_cast(_Float16, u);
    return (float)h;
}
__device__ __forceinline__ float sigmoid_f(float x) { return 1.0f / (1.0f + __expf(-x)); }

// load 8 consecutive f32, convert to packed f16 frag via v_cvt_pkrtz
__device__ __forceinline__ short8 cvt8(const float* p) {
    const float4* q = (const float4*)(const void*)p;
    float4 u = q[0], v = q[1];
    half2v h0 = __builtin_amdgcn_cvt_pkrtz(u.x, u.y);
    half2v h1 = __builtin_amdgcn_cvt_pkrtz(u.z, u.w);
    half2v h2 = __builtin_amdgcn_cvt_pkrtz(v.x, v.y);
    half2v h3 = __builtin_amdgcn_cvt_pkrtz(v.z, v.w);
    int4 pk = { __builtin_bit_cast(int, h0), __builtin_bit_cast(int, h1),
                __builtin_bit_cast(int, h2), __builtin_bit_cast(int, h3) };
    return __builtin_bit_cast(short8, pk);
}

// broadcast-read reductions over a 16-float LDS row (uniform addr per lane group)
__device__ __forceinline__ float max16f(const float* p) {
    const float4* q = (const float4*)(const void*)p;
    float4 a = q[0], b = q[1], c = q[2], d = q[3];
    float m0 = fmaxf(fmaxf(a.x, a.y), fmaxf(a.z, a.w));
    float m1 = fmaxf(fmaxf(b.x, b.y), fmaxf(b.z, b.w));
    float m2 = fmaxf(fmaxf(c.x, c.y), fmaxf(c.z, c.w));
    float m3 = fmaxf(fmaxf(d.x, d.y), fmaxf(d.z, d.w));
    return fmaxf(fmaxf(m0, m1), fmaxf(m2, m3));
}
__device__ __forceinline__ float sum16f(const float* p) {
    const float4* q = (const float4*)(const void*)p;
    float4 a = q[0], b = q[1], c = q[2], d = q[3];
    return ((a.x + a.y) + (a.z + a.w)) + ((b.x + b.y) + (b.z + b.w))
         + ((c.x + c.y) + (c.z + c.w)) + ((d.x + d.y) + (d.z + d.w));
}

// ---------------------------------------------------------------------------
// Frag layouts (one wave frag load = 64 lanes x 16 B = 1 KB contiguous):
//   B operand M[n][k]: lane = (n&15) | (((k>>3)&3)<<4), j = k&7
//     W  (n 32 ct, k 24 kt): frag = ((ct>>3)*24 + kt)*8 + (ct&7)
//     la (n 16 lt, k 16 kt): frag = ((lt>>2)*16 + kt)*4 + (lt&3)
//     lt (n 32 ct, k  8 kt): frag = ((ct>>3)*8  + kt)*8 + (ct&7)
//   A operand x[m][k]: lane = (m&15) | (((k>>3)&3)<<4), j = k&7
//     x  (m 2048 mt, k 24 kt): frag = mt*24 + kt
// ---------------------------------------------------------------------------

// Kernel 0: x-repack (blocks < xblocks) + Wi/Wia repack (tail blocks).
// x part: coalesced float4 reads -> LDS transpose tile -> coalesced short8 writes.
__global__ __launch_bounds__(256) void prep_xw(
    const float* __restrict__ x,
    const float* __restrict__ Wi, const float* __restrict__ Wia,
    unsigned short* __restrict__ x_f,
    unsigned short* __restrict__ Wi_f, unsigned short* __restrict__ Wia_f,
    int xblocks)
{
    __shared__ unsigned short tile[16 * XP_STRIDE];   // 24.8 KB (x part only)
    const int t = threadIdx.x;
    if ((int)blockIdx.x < xblocks) {
        const int mt = blockIdx.x;                    // 0..2047, 16 rows each
        const float4* src = (const float4*)(const void*)(x + (size_t)mt * 16 * H_DIM);
#pragma unroll
        for (int i = 0; i < 12; ++i) {
            const int id  = i * 256 + t;              // 0..3071 float4 chunks
            const int row = id / 192;
            const int c4  = id - row * 192;
            float4 v = src[id];                       // consecutive lanes -> coalesced
            half2v h0 = __builtin_amdgcn_cvt_pkrtz(v.x, v.y);
            half2v h1 = __builtin_amdgcn_cvt_pkrtz(v.z, v.w);
            uint2 pk = { __builtin_bit_cast(unsigned int, h0),
                         __builtin_bit_cast(unsigned int, h1) };
            *(uint2*)(void*)(tile + row * XP_STRIDE + c4 * 4) = pk;
        }
        __syncthreads();
        const int lane = t & 63;
        const int wave = t >> 6;
#pragma unroll
        for (int q = 0; q < 6; ++q) {
            const int kt = wave * 6 + q;              // 4 waves x 6 = 24 frags
            short8 v = *(const short8*)(const void*)(
                tile + (lane & 15) * XP_STRIDE + kt * 32 + (lane >> 4) * 8);
            *(short8*)(void*)(x_f + ((size_t)(mt * 24 + kt) * 64 + lane) * 8) = v;
        }
    } else {
        const int tid = (blockIdx.x - xblocks) * 256 + t;  // over 2*49152
        const int m   = tid / 49152;
        const int idx = tid - m * 49152;
        const int ct   = idx / 1536;          // 0..31
        const int rem  = idx - ct * 1536;
        const int kt   = rem >> 6;            // 0..23
        const int lane = rem & 63;
        const int row  = ct * 16 + (lane & 15);
        const int kcol = kt * 32 + (lane >> 4) * 8;
        const float* src = (m == 0 ? Wi : Wia);
        unsigned short* dst = (m == 0 ? Wi_f : Wia_f);
        short8 v = cvt8(src + (size_t)row * H_DIM + kcol);
        const int frag = ((ct >> 3) * 24 + kt) * 8 + (ct & 7);
        *(short8*)(void*)(dst + ((size_t)frag * 64 + lane) * 8) = v;
    }
}

// ---------------------------------------------------------------------------
// Kernel 1: label-side joint MFMA GEMM; reads Wl/Wla raw f32 (tiny kernel,
// no prepack needed). Grid 64 = 8 c-tiles(64) x 8 l-blocks(32).
// ---------------------------------------------------------------------------
__global__ __launch_bounds__(256) void label_mfma(
    const float* __restrict__ lab,
    const float* __restrict__ Wl,  const float* __restrict__ bl,
    const float* __restrict__ Wla, const float* __restrict__ bla,
    const float* __restrict__ ctx,
    unsigned short* __restrict__ la_f,
    unsigned short* __restrict__ lt_f)
{
    const int tid  = threadIdx.x;
    const int wave = tid >> 6;
    const int lane = tid & 63;
    const int quad = lane >> 4;
    const int c16  = lane & 15;
    const int ct2  = blockIdx.x & 7;
    const int mh   = blockIdx.x >> 3;    // 0..7
    const int ct   = ct2 * 4 + wave;     // 0..31
    const int n0   = ct * 16;
    const int l0   = mh * 32;

    const f32x4 z4 = {0.f, 0.f, 0.f, 0.f};
    f32x4 a1[2], a2[2];
#pragma unroll
    for (int mt = 0; mt < 2; ++mt) { a1[mt] = z4; a2[mt] = z4; }

    const float* lb   = lab + (size_t)(l0 + c16) * H_DIM + quad * 8;
    const float* wlp  = Wl  + (size_t)(n0 + c16) * H_DIM + quad * 8;
    const float* wlap = Wla + (size_t)(n0 + c16) * H_DIM + quad * 8;
    for (int kt = 0; kt < 24; ++kt) {
        short8 b1 = cvt8(wlp + kt * 32);
        short8 b2 = cvt8(wlap + kt * 32);
#pragma unroll
        for (int mt = 0; mt < 2; ++mt) {
            short8 a = cvt8(lb + mt * 16 * H_DIM + kt * 32);
            a1[mt] = MFMA_F16(a, b1, a1[mt]);
            a2[mt] = MFMA_F16(a, b2, a2[mt]);
        }
    }
    const int c = n0 + c16;
    const float blv = bl[c], blav = bla[c], cv = ctx[c];
#pragma unroll
    for (int mt = 0; mt < 2; ++mt)
#pragma unroll
        for (int r = 0; r < 4; ++r) {
            const int l = l0 + mt * 16 + quad * 4 + r;
            const float ltv = sigmoid_f(a1[mt][r] + blv);
            const float lav = sigmoid_f(a2[mt][r] + blav) * cv;
            {   // lt_f: n=c, k=l
                const int ctc = c >> 4, ktl = l >> 5;
                const int frag = ((ctc >> 3) * 8 + ktl) * 8 + (ctc & 7);
                const int ln = (c & 15) | (((l >> 3) & 3) << 4);
                lt_f[((size_t)frag * 64 + ln) * 8 + (l & 7)] = f2h(ltv);
            }
            {   // la_f: n=l, k=c
                const int lt = l >> 4, ktc = c >> 5;
                const int frag = ((lt >> 2) * 16 + ktc) * 4 + (lt & 3);
                const int ln = (l & 15) | (((c >> 3) & 3) << 4);
                la_f[((size_t)frag * 64 + ln) * 8 + (c & 7)] = f2h(lav);
            }
        }
}

// ---------------------------------------------------------------------------
// Kernel 2: fused main v3. One block = 64 rows, 16 waves (1024 thr), 1/CU.
// P1+P5 MERGED: per kt, one x-frag stream feeds BOTH ia (Wia) and it (Wi)
// accumulators (wave = m4 x nt2, acc 32+32 regs). it -> sigmoid -> packed
// f16 in 16 regs, carried to the end: no wgt LDS spill/re-read, x_f read
// once, one 24-kt loop instead of two, 4 barriers instead of 8.
// Unified reg budget must stay <=128/wave (16 waves/CU hard cap).
// ---------------------------------------------------------------------------
template<bool XF>
__global__ __launch_bounds__(1024) void fused_main(
    const unsigned short* __restrict__ x_f,     // A-frag f16 (XF only)
    const float* __restrict__ x,                // f32 (fallback only)
    const float* __restrict__ bi,
    const float* __restrict__ bia,
    const unsigned short* __restrict__ Wi_f,
    const unsigned short* __restrict__ Wia_f,
    const unsigned short* __restrict__ lt_f,
    const unsigned short* __restrict__ la_f,
    float* __restrict__ fusion)                 // f32 [B][C]
{
    __shared__ unsigned short lds_buf[64 * IA_STRIDE]; // 66.6 KB: ia then attn
    __shared__ float scratchA[64 * 16];                // per-wave row maxima
    __shared__ float scratchB[64 * 16];                // per-wave row sums

    const int tid  = threadIdx.x;
    const int wave = tid >> 6;      // 0..15
    const int lane = tid & 63;
    const int quad = lane >> 4;
    const int c16  = lane & 15;

    const int row0 = blockIdx.x * 64;
    const int b    = row0 >> 11;   // / 2048

    const f32x4 z4 = {0.f, 0.f, 0.f, 0.f};
    const int n0  = wave * 32;     // C-column split (nt 0..1)
    const int ct0 = wave * 2;      // even -> ct0,ct0+1 share frag block

    const float*  xb  = x + (size_t)(row0 + c16) * H_DIM + quad * 8;
    const short8* xf8 = (const short8*)(const void*)x_f + (size_t)blockIdx.x * 96 * 64 + lane;
    const size_t wofs = ((size_t)(ct0 >> 3) * 192 + (ct0 & 7)) * 64 + lane;
    const short8* wa8 = (const short8*)(const void*)Wia_f + wofs;
    const short8* wi8 = (const short8*)(const void*)Wi_f  + wofs;

    unsigned int it_h[4][2][2];    // it = sigmoid(x@Wi^T+bi), f16-packed, 16 regs

    // ========== Phase 1 (merged): ia AND it GEMMs over K=768 ==============
    {
        f32x4 aa[4][2], at[4][2];
#pragma unroll
        for (int m = 0; m < 4; ++m)
#pragma unroll
            for (int nt = 0; nt < 2; ++nt) { aa[m][nt] = z4; at[m][nt] = z4; }
        for (int kt = 0; kt < 24; ++kt) {
            short8 a0, a1, a2, a3;
            if constexpr (XF) {
                a0 = xf8[kt * 64];        a1 = xf8[(24 + kt) * 64];
                a2 = xf8[(48 + kt) * 64]; a3 = xf8[(72 + kt) * 64];
            } else {
                a0 = cvt8(xb + kt * 32);                a1 = cvt8(xb + 16 * H_DIM + kt * 32);
                a2 = cvt8(xb + 32 * H_DIM + kt * 32);   a3 = cvt8(xb + 48 * H_DIM + kt * 32);
            }
            const int ko = kt * 512;
            {
                short8 ba = wa8[ko], bt = wi8[ko];
                aa[0][0] = MFMA_F16(a0, ba, aa[0][0]);
                aa[1][0] = MFMA_F16(a1, ba, aa[1][0]);
                aa[2][0] = MFMA_F16(a2, ba, aa[2][0]);
                aa[3][0] = MFMA_F16(a3, ba, aa[3][0]);
                at[0][0] = MFMA_F16(a0, bt, at[0][0]);
                at[1][0] = MFMA_F16(a1, bt, at[1][0]);
                at[2][0] = MFMA_F16(a2, bt, at[2][0]);
                at[3][0] = MFMA_F16(a3, bt, at[3][0]);
            }
            {
                short8 ba = wa8[ko + 64], bt = wi8[ko + 64];
                aa[0][1] = MFMA_F16(a0, ba, aa[0][1]);
                aa[1][1] = MFMA_F16(a1, ba, aa[1][1]);
                aa[2][1] = MFMA_F16(a2, ba, aa[2][1]);
                aa[3][1] = MFMA_F16(a3, ba, aa[3][1]);
                at[0][1] = MFMA_F16(a0, bt, at[0][1]);
                at[1][1] = MFMA_F16(a1, bt, at[1][1]);
                at[2][1] = MFMA_F16(a2, bt, at[2][1]);
                at[3][1] = MFMA_F16(a3, bt, at[3][1]);
            }
        }
#pragma unroll
        for (int nt = 0; nt < 2; ++nt) {
            const int col = n0 + nt * 16 + c16;
            const float bav = bia[col], biv = bi[col];
#pragma unroll
            for (int m = 0; m < 4; ++m) {
#pragma unroll
                for (int r = 0; r < 4; ++r) {
                    const int row = m * 16 + quad * 4 + r;
                    lds_buf[row * IA_STRIDE + col] = f2h(sigmoid_f(aa[m][nt][r] + bav));
                }
                const float t0 = sigmoid_f(at[m][nt][0] + biv);
                const float t1 = sigmoid_f(at[m][nt][1] + biv);
                const float t2 = sigmoid_f(at[m][nt][2] + biv);
                const float t3 = sigmoid_f(at[m][nt][3] + biv);
                it_h[m][nt][0] = __builtin_bit_cast(unsigned int, __builtin_amdgcn_cvt_pkrtz(t0, t1));
                it_h[m][nt][1] = __builtin_bit_cast(unsigned int, __builtin_amdgcn_cvt_pkrtz(t2, t3));
            }
        }
    }
    __syncthreads();

    // ========== Phase 2: logits = ia @ la^T (K=512), 16 L-cols/wave =======
    f32x4 accl[4];
#pragma unroll
    for (int m = 0; m < 4; ++m) accl[m] = z4;
    {
        const unsigned short* ab = lds_buf + c16 * IA_STRIDE + quad * 8;
        const short8* la8 = (const short8*)(const void*)la_f
                          + ((size_t)(wave >> 2) * 64 + (wave & 3)) * 64 + lane;
        for (int kt = 0; kt < 16; ++kt) {
            const int kk = kt * 32;
            short8 a0 = *(const short8*)(const void*)(ab + kk);
            short8 a1 = *(const short8*)(const void*)(ab + 16 * IA_STRIDE + kk);
            short8 a2 = *(const short8*)(const void*)(ab + 32 * IA_STRIDE + kk);
            short8 a3 = *(const short8*)(const void*)(ab + 48 * IA_STRIDE + kk);
            short8 bfr = la8[kt * 256];
            accl[0] = MFMA_F16(a0, bfr, accl[0]);
            accl[1] = MFMA_F16(a1, bfr, accl[1]);
            accl[2] = MFMA_F16(a2, bfr, accl[2]);
            accl[3] = MFMA_F16(a3, bfr, accl[3]);
        }
    }
    __syncthreads();   // all ia reads complete; lds_buf reusable for attn

    // ========== Phase 3: softmax over L (unnormalized; keep 1/sum) ========
    // 3a: per-wave row maxima -> scratchA[row][wave]
#pragma unroll
    for (int m = 0; m < 4; ++m)
#pragma unroll
        for (int r = 0; r < 4; ++r) {
            float mx = accl[m][r];
#pragma unroll
            for (int off = 1; off < 16; off <<= 1) mx = fmaxf(mx, __shfl_xor(mx, off, 64));
            if (c16 == 0) scratchA[(m * 16 + quad * 4 + r) * 16 + wave] = mx;
        }
    __syncthreads();
    // 3b: global max (broadcast read), exp, attn f16 -> LDS, per-wave sums
#pragma unroll
    for (int m = 0; m < 4; ++m)
#pragma unroll
        for (int r = 0; r < 4; ++r) {
            const int row = m * 16 + quad * 4 + r;
            const float gm = max16f(&scratchA[row * 16]);
            float e = __expf(accl[m][r] - gm);
            lds_buf[row * ATTN_STRIDE + wave * 16 + c16] = f2h(e);
#pragma unroll
            for (int off = 1; off < 16; off <<= 1) e += __shfl_xor(e, off, 64);
            if (c16 == 0) scratchB[row * 16 + wave] = e;
        }
    __syncthreads();   // attn + sums visible
    // 3c: per-row inverse sums (broadcast read, kept in regs)
    float invr[4][4];
#pragma unroll
    for (int m = 0; m < 4; ++m)
#pragma unroll
        for (int r = 0; r < 4; ++r) {
            const int row = m * 16 + quad * 4 + r;
            invr[m][r] = 1.0f / sum16f(&scratchB[row * 16]);
        }

    // ========== Phase 4: weighted = attn @ lt (K=256), 32 C-cols/wave =====
    f32x4 accw[4][2];
#pragma unroll
    for (int m = 0; m < 4; ++m)
#pragma unroll
        for (int nt = 0; nt < 2; ++nt) accw[m][nt] = z4;
    {
        const unsigned short* ab = lds_buf + c16 * ATTN_STRIDE + quad * 8;
        const short8* lt8 = (const short8*)(const void*)lt_f
                          + ((size_t)(ct0 >> 3) * 64 + (ct0 & 7)) * 64 + lane;
        for (int kt = 0; kt < 8; ++kt) {
            const int kk = kt * 32;
            short8 a0 = *(const short8*)(const void*)(ab + kk);
            short8 a1 = *(const short8*)(const void*)(ab + 16 * ATTN_STRIDE + kk);
            short8 a2 = *(const short8*)(const void*)(ab + 32 * ATTN_STRIDE + kk);
            short8 a3 = *(const short8*)(const void*)(ab + 48 * ATTN_STRIDE + kk);
            short8 b0 = lt8[kt * 512], b1 = lt8[kt * 512 + 64];
            accw[0][0] = MFMA_F16(a0, b0, accw[0][0]);
            accw[1][0] = MFMA_F16(a1, b0, accw[1][0]);
            accw[2][0] = MFMA_F16(a2, b0, accw[2][0]);
            accw[3][0] = MFMA_F16(a3, b0, accw[3][0]);
            accw[0][1] = MFMA_F16(a0, b1, accw[0][1]);
            accw[1][1] = MFMA_F16(a1, b1, accw[1][1]);
            accw[2][1] = MFMA_F16(a2, b1, accw[2][1]);
            accw[3][1] = MFMA_F16(a3, b1, accw[3][1]);
        }
    }

    // ========== Epilogue: fusion[b][col] += sum_rows wgt * it (regs only) ==
#pragma unroll
    for (int nt = 0; nt < 2; ++nt) {
        const int col = n0 + nt * 16 + c16;
        float s = 0.f;
#pragma unroll
        for (int m = 0; m < 4; ++m) {
            const unsigned int u0 = it_h[m][nt][0], u1 = it_h[m][nt][1];
            const float t0 = h2f((unsigned short)(u0 & 0xffff));
            const float t1 = h2f((unsigned short)(u0 >> 16));
            const float t2 = h2f((unsigned short)(u1 & 0xffff));
            const float t3 = h2f((unsigned short)(u1 >> 16));
            s += accw[m][nt][0] * invr[m][0] * t0;
            s += accw[m][nt][1] * invr[m][1] * t1;
            s += accw[m][nt][2] * invr[m][2] * t2;
            s += accw[m][nt][3] * invr[m][3] * t3;
        }
        s += __shfl_xor(s, 16, 64);
        s += __shfl_xor(s, 32, 64);
        if (lane < 16) atomicAdd(&fusion[b * C_DIM + col], s);
    }
}

// ---------------------------------------------------------------------------
// Kernel 3: out[b][h] = sum_c fusion[b][c] * Wp[h][c]. 8 lanes per row.
// ---------------------------------------------------------------------------
__global__ __launch_bounds__(256) void out_kernel(
    const float* __restrict__ fusion,
    const float* __restrict__ Wp,
    float* __restrict__ out)
{
    const int idx = blockIdx.x * 256 + threadIdx.x;
    const int R   = idx >> 3;
    const int sub = idx & 7;
    const int bb  = R / H_DIM;
    const int h   = R - bb * H_DIM;
    const float* wp = Wp + (size_t)h * C_DIM;
    const float* f  = fusion + bb * C_DIM;
    float s = 0.f;
#pragma unroll
    for (int j = 0; j < 16; ++j) {
        const int c = j * 32 + sub * 4;
        float4 wv = *(const float4*)(const void*)(wp + c);
        float4 fv = *(const float4*)(const void*)(f + c);
        s += fv.x * wv.x + fv.y * wv.y + fv.z * wv.z + fv.w * wv.w;
    }
    s += __shfl_xor(s, 1, 64);
    s += __shfl_xor(s, 2, 64);
    s += __shfl_xor(s, 4, 64);
    if (sub == 0) out[R] = s;
}

extern "C" void kernel_launch(void* const* d_in, const int* in_sizes, int n_in,
                              void* d_out, int out_size, void* d_ws, size_t ws_size,
                              hipStream_t stream)
{
    const float* x    = (const float*)d_in[0];
    const float* lab  = (const float*)d_in[1];
    const float* Wi   = (const float*)d_in[2];
    const float* bi   = (const float*)d_in[3];
    const float* Wl   = (const float*)d_in[4];
    const float* bl   = (const float*)d_in[5];
    const float* Wia  = (const float*)d_in[6];
    const float* bia  = (const float*)d_in[7];
    const float* Wla  = (const float*)d_in[8];
    const float* bla  = (const float*)d_in[9];
    const float* ctx  = (const float*)d_in[10];
    const float* Wp   = (const float*)d_in[11];

    char* ws = (char*)d_ws;
    unsigned short* Wi_f  = (unsigned short*)(ws);               // 768 KB
    unsigned short* Wia_f = (unsigned short*)(ws + 786432);      // 768 KB
    unsigned short* la_f  = (unsigned short*)(ws + 3145728);     // 256 KB
    unsigned short* lt_f  = (unsigned short*)(ws + 3407872);     // 256 KB
    float* fusion         = (float*)(ws + 3670016);              // 32 KB
    unsigned short* x_f   = (unsigned short*)(ws + 3702784);     // 48 MB (optional)
    const size_t NEED_XF  = 3702784 + (size_t)32768 * 768 * 2;   // ~51.5 MB

    (void)hipMemsetAsync(fusion, 0, B_DIM * C_DIM * sizeof(float), stream);
    label_mfma<<<64, 256, 0, stream>>>(lab, Wl, bl, Wla, bla, ctx, la_f, lt_f);
    if (ws_size >= NEED_XF) {
        prep_xw<<<2048 + 384, 256, 0, stream>>>(x, Wi, Wia, x_f, Wi_f, Wia_f, 2048);
        fused_main<true><<<(B_DIM * S_DIM) / 64, 1024, 0, stream>>>(
            x_f, x, bi, bia, Wi_f, Wia_f, lt_f, la_f, fusion);
    } else {
        prep_xw<<<384, 256, 0, stream>>>(x, Wi, Wia, x_f, Wi_f, Wia_f, 0);
        fused_main<false><<<(B_DIM * S_DIM) / 64, 1024, 0, stream>>>(
            nullptr, x, bi, bia, Wi_f, Wia_f, lt_f, la_f, fusion);
    }
    out_kernel<<<384, 256, 0, stream>>>(fusion, Wp, (float*)d_out);
}

// Round 5
// 299.404 us; speedup vs baseline: 1.0374x; 1.0374x over previous
//
#include <hip/hip_runtime.h>

#define H_DIM 768
#define C_DIM 512
#define L_DIM 256
#define S_DIM 2048
#define B_DIM 16

#define IA_STRIDE 520   // 512 + 8: lane stride 1040B = 260 dw = 4 mod 32 banks
#define ATTN_STRIDE 264 // 256 + 8: lane stride 528B = 132 dw = 4 mod 32 banks
#define XP_STRIDE 776   // 768 + 8 (f16): row stride 1552B, 16B-aligned, 2-way conflict (free)

typedef __attribute__((ext_vector_type(8))) short short8;
typedef __attribute__((ext_vector_type(4))) float f32x4;
typedef __attribute__((ext_vector_type(2))) __fp16 half2v;   // cvt_pkrtz return type

#define MFMA_F16(a, b, c) __builtin_amdgcn_mfma_f32_16x16x32_f16((a), (b), (c), 0, 0, 0)

__device__ __forceinline__ unsigned short f2h(float f) {
    _Float16 h = (_Float16)f;
    return __builtin_bit_cast(unsigned short, h);
}
__device__ __forceinline__ float h2f(unsigned short u) {
    _Float16 h = __builtin_bit_cast(_Float16, u);
    return (float)h;
}
__device__ __forceinline__ float sigmoid_f(float x) { return 1.0f / (1.0f + __expf(-x)); }

// load 8 consecutive f32, convert to packed f16 frag via v_cvt_pkrtz
__device__ __forceinline__ short8 cvt8(const float* p) {
    const float4* q = (const float4*)(const void*)p;
    float4 u = q[0], v = q[1];
    half2v h0 = __builtin_amdgcn_cvt_pkrtz(u.x, u.y);
    half2v h1 = __builtin_amdgcn_cvt_pkrtz(u.z, u.w);
    half2v h2 = __builtin_amdgcn_cvt_pkrtz(v.x, v.y);
    half2v h3 = __builtin_amdgcn_cvt_pkrtz(v.z, v.w);
    int4 pk = { __builtin_bit_cast(int, h0), __builtin_bit_cast(int, h1),
                __builtin_bit_cast(int, h2), __builtin_bit_cast(int, h3) };
    return __builtin_bit_cast(short8, pk);
}

// ---------------------------------------------------------------------------
// Frag layouts (one wave frag load = 64 lanes x 16 B = 1 KB contiguous):
//   B operand M[n][k]: lane = (n&15) | (((k>>3)&3)<<4), j = k&7
//     W  (n 32 ct, k 24 kt): frag = ((ct>>3)*24 + kt)*8 + (ct&7)
//     la (n 16 lt, k 16 kt): frag = ((lt>>2)*16 + kt)*4 + (lt&3)
//     lt (n 32 ct, k  8 kt): frag = ((ct>>3)*8  + kt)*8 + (ct&7)
//   A operand x[m][k]: lane = (m&15) | (((k>>3)&3)<<4), j = k&7
//     x  (m 2048 mt, k 24 kt): frag = mt*24 + kt
// ---------------------------------------------------------------------------

// Kernel 0: x-repack (blocks < xblocks) + Wi/Wia repack (tail blocks).
// x part: coalesced float4 reads -> LDS transpose tile -> coalesced short8 writes.
__global__ __launch_bounds__(256) void prep_xw(
    const float* __restrict__ x,
    const float* __restrict__ Wi, const float* __restrict__ Wia,
    unsigned short* __restrict__ x_f,
    unsigned short* __restrict__ Wi_f, unsigned short* __restrict__ Wia_f,
    int xblocks)
{
    __shared__ unsigned short tile[16 * XP_STRIDE];   // 24.8 KB
    const int t = threadIdx.x;
    if ((int)blockIdx.x < xblocks) {
        const int mt = blockIdx.x;                    // 0..2047, 16 rows each
        const float4* src = (const float4*)(const void*)(x + (size_t)mt * 16 * H_DIM);
#pragma unroll
        for (int i = 0; i < 12; ++i) {
            const int id  = i * 256 + t;              // 0..3071 float4 chunks
            const int row = id / 192;
            const int c4  = id - row * 192;
            float4 v = src[id];                       // consecutive lanes -> coalesced
            half2v h0 = __builtin_amdgcn_cvt_pkrtz(v.x, v.y);
            half2v h1 = __builtin_amdgcn_cvt_pkrtz(v.z, v.w);
            uint2 pk = { __builtin_bit_cast(unsigned int, h0),
                         __builtin_bit_cast(unsigned int, h1) };
            *(uint2*)(void*)(tile + row * XP_STRIDE + c4 * 4) = pk;
        }
        __syncthreads();
        const int lane = t & 63;
        const int wave = t >> 6;
#pragma unroll
        for (int q = 0; q < 6; ++q) {
            const int kt = wave * 6 + q;              // 4 waves x 6 = 24 frags
            short8 v = *(const short8*)(const void*)(
                tile + (lane & 15) * XP_STRIDE + kt * 32 + (lane >> 4) * 8);
            *(short8*)(void*)(x_f + ((size_t)(mt * 24 + kt) * 64 + lane) * 8) = v;
        }
    } else {
        const int tid = (blockIdx.x - xblocks) * 256 + t;  // over 2*49152
        const int m   = tid / 49152;
        const int idx = tid - m * 49152;
        const int ct   = idx / 1536;          // 0..31
        const int rem  = idx - ct * 1536;
        const int kt   = rem >> 6;            // 0..23
        const int lane = rem & 63;
        const int row  = ct * 16 + (lane & 15);
        const int kcol = kt * 32 + (lane >> 4) * 8;
        const float* src = (m == 0 ? Wi : Wia);
        unsigned short* dst = (m == 0 ? Wi_f : Wia_f);
        short8 v = cvt8(src + (size_t)row * H_DIM + kcol);
        const int frag = ((ct >> 3) * 24 + kt) * 8 + (ct & 7);
        *(short8*)(void*)(dst + ((size_t)frag * 64 + lane) * 8) = v;
    }
}

// ---------------------------------------------------------------------------
// Kernel 1: label-side joint MFMA GEMM; reads Wl/Wla raw f32 (tiny kernel,
// no prepack needed). Grid 64 = 8 c-tiles(64) x 8 l-blocks(32).
// ---------------------------------------------------------------------------
__global__ __launch_bounds__(256) void label_mfma(
    const float* __restrict__ lab,
    const float* __restrict__ Wl,  const float* __restrict__ bl,
    const float* __restrict__ Wla, const float* __restrict__ bla,
    const float* __restrict__ ctx,
    unsigned short* __restrict__ la_f,
    unsigned short* __restrict__ lt_f)
{
    const int tid  = threadIdx.x;
    const int wave = tid >> 6;
    const int lane = tid & 63;
    const int quad = lane >> 4;
    const int c16  = lane & 15;
    const int ct2  = blockIdx.x & 7;
    const int mh   = blockIdx.x >> 3;    // 0..7
    const int ct   = ct2 * 4 + wave;     // 0..31
    const int n0   = ct * 16;
    const int l0   = mh * 32;

    const f32x4 z4 = {0.f, 0.f, 0.f, 0.f};
    f32x4 a1[2], a2[2];
#pragma unroll
    for (int mt = 0; mt < 2; ++mt) { a1[mt] = z4; a2[mt] = z4; }

    const float* lb   = lab + (size_t)(l0 + c16) * H_DIM + quad * 8;
    const float* wlp  = Wl  + (size_t)(n0 + c16) * H_DIM + quad * 8;
    const float* wlap = Wla + (size_t)(n0 + c16) * H_DIM + quad * 8;
    for (int kt = 0; kt < 24; ++kt) {
        short8 b1 = cvt8(wlp + kt * 32);
        short8 b2 = cvt8(wlap + kt * 32);
#pragma unroll
        for (int mt = 0; mt < 2; ++mt) {
            short8 a = cvt8(lb + mt * 16 * H_DIM + kt * 32);
            a1[mt] = MFMA_F16(a, b1, a1[mt]);
            a2[mt] = MFMA_F16(a, b2, a2[mt]);
        }
    }
    const int c = n0 + c16;
    const float blv = bl[c], blav = bla[c], cv = ctx[c];
#pragma unroll
    for (int mt = 0; mt < 2; ++mt)
#pragma unroll
        for (int r = 0; r < 4; ++r) {
            const int l = l0 + mt * 16 + quad * 4 + r;
            const float ltv = sigmoid_f(a1[mt][r] + blv);
            const float lav = sigmoid_f(a2[mt][r] + blav) * cv;
            {   // lt_f: n=c, k=l
                const int ctc = c >> 4, ktl = l >> 5;
                const int frag = ((ctc >> 3) * 8 + ktl) * 8 + (ctc & 7);
                const int ln = (c & 15) | (((l >> 3) & 3) << 4);
                lt_f[((size_t)frag * 64 + ln) * 8 + (l & 7)] = f2h(ltv);
            }
            {   // la_f: n=l, k=c
                const int lt = l >> 4, ktc = c >> 5;
                const int frag = ((lt >> 2) * 16 + ktc) * 4 + (lt & 3);
                const int ln = (l & 15) | (((c >> 3) & 3) << 4);
                la_f[((size_t)frag * 64 + ln) * 8 + (c & 7)] = f2h(lav);
            }
        }
}

// ---------------------------------------------------------------------------
// Kernel 2: fused main (round-1 version: 64 rows, 8 waves x 64 C-cols,
// 2 blocks/CU for inter-block phase overlap; conflict-free softmax).
// ---------------------------------------------------------------------------
template<bool XF>
__global__ __launch_bounds__(512, 4) void fused_main(
    const unsigned short* __restrict__ x_f,     // A-frag f16 (XF only)
    const float* __restrict__ x,                // f32 (fallback only)
    const float* __restrict__ bi,
    const float* __restrict__ bia,
    const unsigned short* __restrict__ Wi_f,
    const unsigned short* __restrict__ Wia_f,
    const unsigned short* __restrict__ lt_f,
    const unsigned short* __restrict__ la_f,
    float* __restrict__ fusion)                 // f32 [B][C]
{
    __shared__ unsigned short lds_buf[64 * IA_STRIDE]; // 66.6 KB: ia / attn / wgt
    __shared__ float rowscratch[8 * 64];
    __shared__ float inv_lds[64];

    const int tid  = threadIdx.x;
    const int wave = tid >> 6;      // 0..7
    const int lane = tid & 63;
    const int quad = lane >> 4;
    const int c16  = lane & 15;

    const int row0 = blockIdx.x * 64;
    const int b    = row0 >> 11;   // / 2048

    const f32x4 z4 = {0.f, 0.f, 0.f, 0.f};
    const int n0 = wave * 64;      // C-column split (phases 1,4,5)

    const float*  xb  = x + (size_t)(row0 + c16) * H_DIM + quad * 8;
    const short8* xf8 = (const short8*)(const void*)x_f + (size_t)blockIdx.x * 96 * 64 + lane;
    // W frag base for this wave's 4 ct's (ct = wave*4 + nt):
    const size_t wofs = ((size_t)(wave >> 1) * 192 + (size_t)(wave & 1) * 4) * 64 + lane;

    // ========== Phase 1: ia = x@Wia^T (K=768), sigmoid -> LDS =============
    {
        f32x4 acc[4][4];
#pragma unroll
        for (int m = 0; m < 4; ++m)
#pragma unroll
            for (int nt = 0; nt < 4; ++nt) acc[m][nt] = z4;
        const short8* wa8 = (const short8*)(const void*)Wia_f + wofs;
        for (int kt = 0; kt < 24; ++kt) {
            short8 a0, a1, a2, a3;
            if constexpr (XF) {
                a0 = xf8[kt * 64];        a1 = xf8[(24 + kt) * 64];
                a2 = xf8[(48 + kt) * 64]; a3 = xf8[(72 + kt) * 64];
            } else {
                a0 = cvt8(xb + kt * 32);                a1 = cvt8(xb + 16 * H_DIM + kt * 32);
                a2 = cvt8(xb + 32 * H_DIM + kt * 32);   a3 = cvt8(xb + 48 * H_DIM + kt * 32);
            }
#pragma unroll
            for (int nt = 0; nt < 4; ++nt) {
                short8 bw = wa8[(kt * 8 + nt) * 64];
                acc[0][nt] = MFMA_F16(a0, bw, acc[0][nt]);
                acc[1][nt] = MFMA_F16(a1, bw, acc[1][nt]);
                acc[2][nt] = MFMA_F16(a2, bw, acc[2][nt]);
                acc[3][nt] = MFMA_F16(a3, bw, acc[3][nt]);
            }
        }
#pragma unroll
        for (int nt = 0; nt < 4; ++nt) {
            const int col = n0 + nt * 16 + c16;
            const float bv = bia[col];
#pragma unroll
            for (int m = 0; m < 4; ++m)
#pragma unroll
                for (int r = 0; r < 4; ++r) {
                    const int row = m * 16 + quad * 4 + r;
                    lds_buf[row * IA_STRIDE + col] = f2h(sigmoid_f(acc[m][nt][r] + bv));
                }
        }
    }
    __syncthreads();

    // ========== Phase 2: logits = ia @ la^T (K=512) =======================
    const int n0l = wave * 32;   // L-column split (8 waves x 32 = 256)
    f32x4 accl[4][2];
#pragma unroll
    for (int m = 0; m < 4; ++m)
#pragma unroll
        for (int j = 0; j < 2; ++j) accl[m][j] = z4;
    {
        const unsigned short* ab = lds_buf + c16 * IA_STRIDE + quad * 8;
        const short8* la8 = (const short8*)(const void*)la_f
                          + ((size_t)(wave >> 1) * 64 + (size_t)(wave & 1) * 2) * 64 + lane;
        for (int kt = 0; kt < 16; ++kt) {
            const int kk = kt * 32;
            short8 a0 = *(const short8*)(const void*)(ab + kk);
            short8 a1 = *(const short8*)(const void*)(ab + 16 * IA_STRIDE + kk);
            short8 a2 = *(const short8*)(const void*)(ab + 32 * IA_STRIDE + kk);
            short8 a3 = *(const short8*)(const void*)(ab + 48 * IA_STRIDE + kk);
#pragma unroll
            for (int j = 0; j < 2; ++j) {
                short8 bfr = la8[(kt * 4 + j) * 64];
                accl[0][j] = MFMA_F16(a0, bfr, accl[0][j]);
                accl[1][j] = MFMA_F16(a1, bfr, accl[1][j]);
                accl[2][j] = MFMA_F16(a2, bfr, accl[2][j]);
                accl[3][j] = MFMA_F16(a3, bfr, accl[3][j]);
            }
        }
    }
    __syncthreads();   // all ia reads complete; lds_buf reusable

    // ========== Phase 3: softmax over L (unnormalized; keep 1/sum) ========
    float rmax[4][4];
#pragma unroll
    for (int m = 0; m < 4; ++m)
#pragma unroll
        for (int r = 0; r < 4; ++r) {
            float mx = fmaxf(accl[m][0][r], accl[m][1][r]);
#pragma unroll
            for (int off = 1; off < 16; off <<= 1) mx = fmaxf(mx, __shfl_xor(mx, off, 64));
            rmax[m][r] = mx;
        }
    if (c16 == 0) {
#pragma unroll
        for (int m = 0; m < 4; ++m)
#pragma unroll
            for (int r = 0; r < 4; ++r)
                rowscratch[wave * 64 + m * 16 + quad * 4 + r] = rmax[m][r];
    }
    __syncthreads();
    float rsum[4][4];
#pragma unroll
    for (int m = 0; m < 4; ++m)
#pragma unroll
        for (int r = 0; r < 4; ++r) {
            const int row = m * 16 + quad * 4 + r;
            float gm = rowscratch[row];
#pragma unroll
            for (int w = 1; w < 8; ++w) gm = fmaxf(gm, rowscratch[w * 64 + row]);
            float s = 0.f;
#pragma unroll
            for (int j = 0; j < 2; ++j) {
                float e = __expf(accl[m][j][r] - gm);
                accl[m][j][r] = e;
                s += e;
            }
#pragma unroll
            for (int off = 1; off < 16; off <<= 1) s += __shfl_xor(s, off, 64);
            rsum[m][r] = s;
        }
    __syncthreads();   // maxima consumed
    if (c16 == 0) {
#pragma unroll
        for (int m = 0; m < 4; ++m)
#pragma unroll
            for (int r = 0; r < 4; ++r)
                rowscratch[wave * 64 + m * 16 + quad * 4 + r] = rsum[m][r];
    }
    __syncthreads();
#pragma unroll
    for (int m = 0; m < 4; ++m)
#pragma unroll
        for (int r = 0; r < 4; ++r) {
            const int row = m * 16 + quad * 4 + r;
            float st = 0.f;
#pragma unroll
            for (int w = 0; w < 8; ++w) st += rowscratch[w * 64 + row];
            if (wave == 0 && c16 == 0) inv_lds[row] = 1.0f / st;
#pragma unroll
            for (int j = 0; j < 2; ++j)
                lds_buf[row * ATTN_STRIDE + n0l + j * 16 + c16] = f2h(accl[m][j][r]);
        }
    __syncthreads();

    // ========== Phase 4: weighted = attn @ lt (K=256) =====================
    f32x4 accw[4][4];
#pragma unroll
    for (int m = 0; m < 4; ++m)
#pragma unroll
        for (int nt = 0; nt < 4; ++nt) accw[m][nt] = z4;
    {
        const unsigned short* ab = lds_buf + c16 * ATTN_STRIDE + quad * 8;
        const short8* lt8 = (const short8*)(const void*)lt_f
                          + ((size_t)(wave >> 1) * 64 + (size_t)(wave & 1) * 4) * 64 + lane;
        for (int kt = 0; kt < 8; ++kt) {
            const int kk = kt * 32;
            short8 a0 = *(const short8*)(const void*)(ab + kk);
            short8 a1 = *(const short8*)(const void*)(ab + 16 * ATTN_STRIDE + kk);
            short8 a2 = *(const short8*)(const void*)(ab + 32 * ATTN_STRIDE + kk);
            short8 a3 = *(const short8*)(const void*)(ab + 48 * ATTN_STRIDE + kk);
#pragma unroll
            for (int nt = 0; nt < 4; ++nt) {
                short8 bfr = lt8[(kt * 8 + nt) * 64];
                accw[0][nt] = MFMA_F16(a0, bfr, accw[0][nt]);
                accw[1][nt] = MFMA_F16(a1, bfr, accw[1][nt]);
                accw[2][nt] = MFMA_F16(a2, bfr, accw[2][nt]);
                accw[3][nt] = MFMA_F16(a3, bfr, accw[3][nt]);
            }
        }
    }
    __syncthreads();   // all attn reads complete; lds_buf reusable for wgt

    // spill wgt = weighted * invsum to LDS (f16); wave-private cols
    {
        float invr[4][4];
#pragma unroll
        for (int m = 0; m < 4; ++m)
#pragma unroll
            for (int r = 0; r < 4; ++r) invr[m][r] = inv_lds[m * 16 + quad * 4 + r];
#pragma unroll
        for (int nt = 0; nt < 4; ++nt) {
            const int col = n0 + nt * 16 + c16;
#pragma unroll
            for (int m = 0; m < 4; ++m)
#pragma unroll
                for (int r = 0; r < 4; ++r) {
                    const int row = m * 16 + quad * 4 + r;
                    lds_buf[row * IA_STRIDE + col] = f2h(accw[m][nt][r] * invr[m][r]);
                }
        }
    }
    // no barrier: phase 5 reads only this wave's own cols

    // ========== Phase 5: it = x@Wi^T (recompute), fusion + atomics ========
    {
        f32x4 acc[4][4];
#pragma unroll
        for (int m = 0; m < 4; ++m)
#pragma unroll
            for (int nt = 0; nt < 4; ++nt) acc[m][nt] = z4;
        const short8* wi8 = (const short8*)(const void*)Wi_f + wofs;
        for (int kt = 0; kt < 24; ++kt) {
            short8 a0, a1, a2, a3;
            if constexpr (XF) {
                a0 = xf8[kt * 64];        a1 = xf8[(24 + kt) * 64];
                a2 = xf8[(48 + kt) * 64]; a3 = xf8[(72 + kt) * 64];
            } else {
                a0 = cvt8(xb + kt * 32);                a1 = cvt8(xb + 16 * H_DIM + kt * 32);
                a2 = cvt8(xb + 32 * H_DIM + kt * 32);   a3 = cvt8(xb + 48 * H_DIM + kt * 32);
            }
#pragma unroll
            for (int nt = 0; nt < 4; ++nt) {
                short8 bw = wi8[(kt * 8 + nt) * 64];
                acc[0][nt] = MFMA_F16(a0, bw, acc[0][nt]);
                acc[1][nt] = MFMA_F16(a1, bw, acc[1][nt]);
                acc[2][nt] = MFMA_F16(a2, bw, acc[2][nt]);
                acc[3][nt] = MFMA_F16(a3, bw, acc[3][nt]);
            }
        }
#pragma unroll
        for (int nt = 0; nt < 4; ++nt) {
            const int col = n0 + nt * 16 + c16;
            const float bv = bi[col];
            float s = 0.f;
#pragma unroll
            for (int m = 0; m < 4; ++m)
#pragma unroll
                for (int r = 0; r < 4; ++r) {
                    const int row = m * 16 + quad * 4 + r;
                    s += h2f(lds_buf[row * IA_STRIDE + col]) * sigmoid_f(acc[m][nt][r] + bv);
                }
            s += __shfl_xor(s, 16, 64);
            s += __shfl_xor(s, 32, 64);
            if (lane < 16) atomicAdd(&fusion[b * C_DIM + col], s);
        }
    }
}

// ---------------------------------------------------------------------------
// Kernel 3: out[b][h] = sum_c fusion[b][c] * Wp[h][c]. 8 lanes per row.
// ---------------------------------------------------------------------------
__global__ __launch_bounds__(256) void out_kernel(
    const float* __restrict__ fusion,
    const float* __restrict__ Wp,
    float* __restrict__ out)
{
    const int idx = blockIdx.x * 256 + threadIdx.x;
    const int R   = idx >> 3;
    const int sub = idx & 7;
    const int bb  = R / H_DIM;
    const int h   = R - bb * H_DIM;
    const float* wp = Wp + (size_t)h * C_DIM;
    const float* f  = fusion + bb * C_DIM;
    float s = 0.f;
#pragma unroll
    for (int j = 0; j < 16; ++j) {
        const int c = j * 32 + sub * 4;
        float4 wv = *(const float4*)(const void*)(wp + c);
        float4 fv = *(const float4*)(const void*)(f + c);
        s += fv.x * wv.x + fv.y * wv.y + fv.z * wv.z + fv.w * wv.w;
    }
    s += __shfl_xor(s, 1, 64);
    s += __shfl_xor(s, 2, 64);
    s += __shfl_xor(s, 4, 64);
    if (sub == 0) out[R] = s;
}

extern "C" void kernel_launch(void* const* d_in, const int* in_sizes, int n_in,
                              void* d_out, int out_size, void* d_ws, size_t ws_size,
                              hipStream_t stream)
{
    const float* x    = (const float*)d_in[0];
    const float* lab  = (const float*)d_in[1];
    const float* Wi   = (const float*)d_in[2];
    const float* bi   = (const float*)d_in[3];
    const float* Wl   = (const float*)d_in[4];
    const float* bl   = (const float*)d_in[5];
    const float* Wia  = (const float*)d_in[6];
    const float* bia  = (const float*)d_in[7];
    const float* Wla  = (const float*)d_in[8];
    const float* bla  = (const float*)d_in[9];
    const float* ctx  = (const float*)d_in[10];
    const float* Wp   = (const float*)d_in[11];

    char* ws = (char*)d_ws;
    unsigned short* Wi_f  = (unsigned short*)(ws);               // 768 KB
    unsigned short* Wia_f = (unsigned short*)(ws + 786432);      // 768 KB
    unsigned short* la_f  = (unsigned short*)(ws + 3145728);     // 256 KB
    unsigned short* lt_f  = (unsigned short*)(ws + 3407872);     // 256 KB
    float* fusion         = (float*)(ws + 3670016);              // 32 KB
    unsigned short* x_f   = (unsigned short*)(ws + 3702784);     // 48 MB (optional)
    const size_t NEED_XF  = 3702784 + (size_t)32768 * 768 * 2;   // ~51.5 MB

    (void)hipMemsetAsync(fusion, 0, B_DIM * C_DIM * sizeof(float), stream);
    label_mfma<<<64, 256, 0, stream>>>(lab, Wl, bl, Wla, bla, ctx, la_f, lt_f);
    if (ws_size >= NEED_XF) {
        prep_xw<<<2048 + 384, 256, 0, stream>>>(x, Wi, Wia, x_f, Wi_f, Wia_f, 2048);
        fused_main<true><<<(B_DIM * S_DIM) / 64, 512, 0, stream>>>(
            x_f, x, bi, bia, Wi_f, Wia_f, lt_f, la_f, fusion);
    } else {
        prep_xw<<<384, 256, 0, stream>>>(x, Wi, Wia, x_f, Wi_f, Wia_f, 0);
        fused_main<false><<<(B_DIM * S_DIM) / 64, 512, 0, stream>>>(
            nullptr, x, bi, bia, Wi_f, Wia_f, lt_f, la_f, fusion);
    }
    out_kernel<<<384, 256, 0, stream>>>(fusion, Wp, (float*)d_out);
}